// Round 2
// baseline (581.574 us; speedup 1.0000x reference)
//
#include <hip/hip_runtime.h>

// Problem constants
#define M_ROWS  32768   // B*H*W
#define D_DIM   512     // C == latent dim
#define K_CODES 1024
#define HW      1024    // H*W

// Main-kernel tiling
#define POS_TILE 64
#define N_TILE   256
#define K_CHUNK  32
#define CB_STRIDE 260   // 256 + 4 pad

// Exact RNE fp32 mul/add that the compiler cannot contract or reassociate.
__device__ __forceinline__ float fmul32(float a, float b) {
  float r; asm volatile("v_mul_f32 %0, %1, %2" : "=v"(r) : "v"(a), "v"(b)); return r;
}
__device__ __forceinline__ float fadd32(float a, float b) {
  float r; asm volatile("v_add_f32 %0, %1, %2" : "=v"(r) : "v"(a), "v"(b)); return r;
}
// numpy 128-block combine: ((r0+r1)+(r2+r3)) + ((r4+r5)+(r6+r7))
__device__ __forceinline__ float pair8(const float* r) {
  return fadd32(fadd32(fadd32(r[0], r[1]), fadd32(r[2], r[3])),
                fadd32(fadd32(r[4], r[5]), fadd32(r[6], r[7])));
}

// ---------------------------------------------------------------------------
// A[i] = np.sum(z_flat[i]*z_flat[i]) replicating numpy fp32 pairwise order:
// 512 -> 256+256 -> 128-base blocks (8 strided accumulators).
// z is (B, C, H, W); row i needs z[b, c, hw], stride HW between c.
__global__ __launch_bounds__(64) void vq_a(const float* __restrict__ z,
                                           float* __restrict__ A) {
  __shared__ float zs[64 * 68];         // [c 64][pos 64] pad to 68
  const int t  = threadIdx.x;           // position within tile
  const int i0 = blockIdx.x * 64;
  const int b = i0 >> 10, hw0 = i0 & 1023;
  const float* zbase = z + (size_t)b * (D_DIM * HW) + hw0;
  float r8[8], blk[4];
#pragma unroll
  for (int ch = 0; ch < 8; ++ch) {      // 8 chunks of 64 c
    __syncthreads();
    {
      const int l = t & 15, j0 = t >> 4;
#pragma unroll
      for (int jj = 0; jj < 16; ++jj) {
        int j = j0 * 16 + jj;           // c within chunk
        float4 vv = *(const float4*)(zbase + (size_t)(ch * 64 + j) * HW + 4 * l);
        *(float4*)(zs + j * 68 + 4 * l) = vv;
      }
    }
    __syncthreads();
#pragma unroll
    for (int j = 0; j < 64; ++j) {
      const int c = ch * 64 + j;        // compile-time (both loops unrolled)
      float v = zs[j * 68 + t];
      float p = fmul32(v, v);
      const int k = c & 7, m = c & 127;
      if (m < 8) r8[k] = p;
      else       r8[k] = fadd32(r8[k], p);
      if (m == 127) blk[c >> 7] = pair8(r8);
    }
  }
  A[i0 + t] = fadd32(fadd32(blk[0], blk[1]), fadd32(blk[2], blk[3]));
}

// ---------------------------------------------------------------------------
// W[n] = np.sum(cb[n]*cb[n]) with the same exact pairwise order.
__global__ __launch_bounds__(64) void vq_w(const float* __restrict__ cb,
                                           float* __restrict__ W) {
  const int n = blockIdx.x * 64 + threadIdx.x;
  const float* wp = cb + (size_t)n * D_DIM;
  float r8[8], blk[4];
#pragma unroll
  for (int bb = 0; bb < 4; ++bb) {
#pragma unroll
    for (int k = 0; k < 8; ++k) {
      float v = wp[bb * 128 + k];
      r8[k] = fmul32(v, v);
    }
#pragma unroll
    for (int i = 8; i < 128; i += 8)
#pragma unroll
      for (int k = 0; k < 8; ++k) {
        float v = wp[bb * 128 + i + k];
        r8[k] = fadd32(r8[k], fmul32(v, v));
      }
    blk[bb] = pair8(r8);
  }
  W[n] = fadd32(fadd32(blk[0], blk[1]), fadd32(blk[2], blk[3]));
}

// ---------------------------------------------------------------------------
// Main pass: fp32 FMA dots, then d = fl32(fl32(A - 2*M) + W) exactly as the
// numpy reference evaluates it; argmin with first-index tie-break.
__global__ __launch_bounds__(256) void vq_main(
    const float* __restrict__ z, const float* __restrict__ cb,
    const float* __restrict__ A, const float* __restrict__ W,
    float* __restrict__ out_q, float* __restrict__ out_idx)
{
  __shared__ float smem[10368];   // staged tiles; later reused for reduction
  float* zs  = smem;              // [K_CHUNK][64]       c-major z tile
  float* cbs = smem + 2048;       // [K_CHUNK][CB_STRIDE] c-major codebook tile
  __shared__ int bidx[64];

  const int tid = threadIdx.x;
  const int i0  = blockIdx.x * POS_TILE;  // never crosses a batch image
  const int b   = i0 >> 10;
  const int hw0 = i0 & 1023;

  const int pg = tid & 7;    // pos-group: 8 groups x 8 pos = 64
  const int ng = tid >> 3;   // n-group: 32 groups x 8 n = 256

  float m1[8];
  int   bi[8];
  float a8[8];
#pragma unroll
  for (int u = 0; u < 8; ++u) {
    m1[u] = 3.4e38f; bi[u] = 0;
    a8[u] = A[i0 + pg * 8 + u];
  }

  const float* zbase = z + (size_t)b * (D_DIM * HW) + hw0;

  for (int nt = 0; nt < K_CODES / N_TILE; ++nt) {
    float acc[8][8];
#pragma unroll
    for (int u = 0; u < 8; ++u)
#pragma unroll
      for (int v = 0; v < 8; ++v) acc[u][v] = 0.f;

    for (int kc = 0; kc < D_DIM / K_CHUNK; ++kc) {
      const int c0 = kc * K_CHUNK;
      __syncthreads();   // protect LDS from previous iteration's readers
      // stage z chunk: 32 c x 64 pos, c-major
      {
        int l = tid & 15, ccb = tid >> 4;
#pragma unroll
        for (int pass = 0; pass < 2; ++pass) {
          int cc = ccb + pass * 16;
          float4 vv = *(const float4*)(zbase + (size_t)(c0 + cc) * HW + 4 * l);
          *(float4*)(zs + cc * 64 + 4 * l) = vv;
        }
      }
      // stage cb chunk: 256 n x 32 c, transposed to c-major
      {
        int l = tid & 7, nn = tid >> 3;
#pragma unroll
        for (int pass = 0; pass < 8; ++pass) {
          int n = nn + pass * 32;
          float4 vv = *(const float4*)(cb + (size_t)(nt * N_TILE + n) * D_DIM + c0 + 4 * l);
          cbs[(4 * l + 0) * CB_STRIDE + n] = vv.x;
          cbs[(4 * l + 1) * CB_STRIDE + n] = vv.y;
          cbs[(4 * l + 2) * CB_STRIDE + n] = vv.z;
          cbs[(4 * l + 3) * CB_STRIDE + n] = vv.w;
        }
      }
      __syncthreads();
#pragma unroll
      for (int c = 0; c < K_CHUNK; ++c) {
        float zr[8], cr[8];
        *(float4*)&zr[0] = *(const float4*)(zs + c * 64 + pg * 8);
        *(float4*)&zr[4] = *(const float4*)(zs + c * 64 + pg * 8 + 4);
        *(float4*)&cr[0] = *(const float4*)(cbs + c * CB_STRIDE + ng * 8);
        *(float4*)&cr[4] = *(const float4*)(cbs + c * CB_STRIDE + ng * 8 + 4);
#pragma unroll
        for (int u = 0; u < 8; ++u)
#pragma unroll
          for (int v = 0; v < 8; ++v)
            acc[u][v] += zr[u] * cr[v];
      }
    }
    // fold this n-tile: d = fl32(fl32(A - 2*M) + W), argmin ascending n
#pragma unroll
    for (int v = 0; v < 8; ++v) {
      int n = nt * N_TILE + ng * 8 + v;
      float wn = W[n];
#pragma unroll
      for (int u = 0; u < 8; ++u) {
        float t1 = fadd32(a8[u], -2.f * acc[u][v]);  // *2 exact; RNE subtract
        float d  = fadd32(t1, wn);
        if (d < m1[u]) { m1[u] = d; bi[u] = n; }
      }
    }
  }

  // cross-thread reduction: 32 partials per position, lowest index on ties
  __syncthreads();
  float* rm1 = smem;                    // [64][33]
  int*   ri  = (int*)(smem + 2112);     // [64][33]
#pragma unroll
  for (int u = 0; u < 8; ++u) {
    int p = pg * 8 + u;
    rm1[p * 33 + ng] = m1[u];
    ri [p * 33 + ng] = bi[u];
  }
  __syncthreads();
  if (tid < 64) {
    int p = tid;
    float fm1 = rm1[p * 33 + 0];
    int   fi  = ri [p * 33 + 0];
    for (int g = 1; g < 32; ++g) {
      float am1 = rm1[p * 33 + g];
      int   ai  = ri [p * 33 + g];
      if (am1 < fm1 || (am1 == fm1 && ai < fi)) { fm1 = am1; fi = ai; }
    }
    int i = i0 + p;
    out_idx[i] = (float)fi;             // indices stored as float
    bidx[p] = fi;
  }
  __syncthreads();
  // gather: out rows are contiguous codebook rows (reshape has no inverse permute)
  float* outp = out_q + (size_t)i0 * D_DIM;
  for (int j = 0; j < 32; ++j) {
    int f4  = j * 256 + tid;   // float4 index within block's 32768-float region
    int row = f4 >> 7;
    int d4  = f4 & 127;
    float4 vv = *(const float4*)(cb + (size_t)bidx[row] * D_DIM + 4 * d4);
    *(float4*)(outp + 4 * f4) = vv;
  }
}

extern "C" void kernel_launch(void* const* d_in, const int* in_sizes, int n_in,
                              void* d_out, int out_size, void* d_ws, size_t ws_size,
                              hipStream_t stream) {
  const float* z  = (const float*)d_in[0];
  const float* cb = (const float*)d_in[1];
  float* out_q   = (float*)d_out;
  float* out_idx = (float*)d_out + (size_t)M_ROWS * D_DIM;
  float* A = (float*)d_ws;                        // 32768 floats
  float* W = (float*)d_ws + M_ROWS;               // 1024 floats

  vq_a   <<<512, 64, 0, stream>>>(z, A);
  vq_w   <<<16, 64, 0, stream>>>(cb, W);
  vq_main<<<512, 256, 0, stream>>>(z, cb, A, W, out_q, out_idx);
}

// Round 3
// 436.270 us; speedup vs baseline: 1.3331x; 1.3331x over previous
//
#include <hip/hip_runtime.h>
#include <hip/hip_bf16.h>

// Problem constants
#define M_ROWS  32768   // B*H*W
#define D_DIM   512     // C == latent dim
#define K_CODES 1024
#define HW      1024
#define IMG_STRIDE (D_DIM * HW)   // 524288

// d_out scratch layout: zh (33,554,432 B) | zl (33,554,432 B) == out_q region;
// idx region (last 131,072 B) holds real out_idx.
// ws layout (bytes):
#define WH_OFF   0u          // 1 MB  swizzled cb-hi bf16
#define WL_OFF   1048576u    // 1 MB  swizzled cb-lo bf16
#define A_OFF    2097152u    // 128 KB  A[i] (numpy-pairwise)
#define W_OFF    2228224u    // 4 KB    W[n]
#define PK_OFF   2232320u    // 128 KB  packed candidates/flags
#define PART_OFF 2363392u    // 2.5 MB  per-(row,bn) top3 partials

#define WINDOW 1.8e-4f  // > reorder window 1.22e-4 + 2*7.6e-6 split-error bound

// ---- exact RNE fp32 ops the compiler can't contract/reassociate ----
__device__ __forceinline__ float fmul32(float a, float b) {
  float r; asm volatile("v_mul_f32 %0, %1, %2" : "=v"(r) : "v"(a), "v"(b)); return r;
}
__device__ __forceinline__ float fadd32(float a, float b) {
  float r; asm volatile("v_add_f32 %0, %1, %2" : "=v"(r) : "v"(a), "v"(b)); return r;
}
__device__ __forceinline__ float pair8(const float* r) {
  return fadd32(fadd32(fadd32(r[0], r[1]), fadd32(r[2], r[3])),
                fadd32(fadd32(r[4], r[5]), fadd32(r[6], r[7])));
}

__device__ __forceinline__ unsigned short f2bf(float x) {
  __hip_bfloat16 h = __float2bfloat16(x);
  unsigned short u; __builtin_memcpy(&u, &h, 2); return u;
}
__device__ __forceinline__ float bf2f(unsigned short u) {
  __hip_bfloat16 h; __builtin_memcpy(&h, &u, 2); return __bfloat162float(h);
}

typedef __attribute__((ext_vector_type(8))) short b8;
typedef __attribute__((ext_vector_type(4))) float f4;

__device__ __forceinline__ void gl_lds16(const void* g, void* l) {
  __builtin_amdgcn_global_load_lds(
      (const __attribute__((address_space(1))) unsigned int*)g,
      (__attribute__((address_space(3))) unsigned int*)l, 16, 0, 0);
}

// top-3 tracking (values s1<=s2<=s3; indices for first two; first-index ties)
struct T3 { float s1, s2, s3; int n1, n2; };
__device__ __forceinline__ void t3_merge(T3& a, const T3& bb) {
  T3 x = a, y = bb;
  bool bf = (y.s1 < x.s1) || (y.s1 == x.s1 && y.n1 < x.n1);
  if (bf) { T3 t = x; x = y; y = t; }
  float rs2; int rn2; float rs3;
  bool c2 = (y.s1 < x.s2) || (y.s1 == x.s2 && y.n1 < x.n2);
  if (c2) { rs2 = y.s1; rn2 = y.n1; rs3 = fminf(x.s2, y.s2); }
  else    { rs2 = x.s2; rn2 = x.n2; rs3 = fminf(x.s3, y.s1); }
  a.s1 = x.s1; a.n1 = x.n1; a.s2 = rs2; a.n2 = rn2; a.s3 = rs3;
}

// ---------------------------------------------------------------------------
// A[i] = np.sum(z_flat[i]^2), exact numpy fp32 pairwise order (round-2 body,
// re-gridded to 256-thread blocks: 4 independent waves, one 64-pos tile each).
__global__ __launch_bounds__(256) void vq_a(const float* __restrict__ z,
                                            float* __restrict__ A) {
  __shared__ float zs[4][64 * 68];
  const int wave = threadIdx.x >> 6, t = threadIdx.x & 63;
  const int i0 = blockIdx.x * 256 + wave * 64;
  const int b = i0 >> 10, hw0 = i0 & 1023;
  const float* zbase = z + (size_t)b * IMG_STRIDE + hw0;
  float* zsw = zs[wave];
  float r8[8], blk[4];
#pragma unroll
  for (int ch = 0; ch < 8; ++ch) {
    __syncthreads();
    {
      const int l = t & 15, j0 = t >> 4;
#pragma unroll
      for (int jj = 0; jj < 16; ++jj) {
        int j = j0 * 16 + jj;
        float4 vv = *(const float4*)(zbase + (size_t)(ch * 64 + j) * HW + 4 * l);
        *(float4*)(zsw + j * 68 + 4 * l) = vv;
      }
    }
    __syncthreads();
#pragma unroll
    for (int j = 0; j < 64; ++j) {
      const int c = ch * 64 + j;
      float v = zsw[j * 68 + t];
      float pq = fmul32(v, v);
      const int k = c & 7, m = c & 127;
      if (m < 8) r8[k] = pq;
      else       r8[k] = fadd32(r8[k], pq);
      if (m == 127) blk[c >> 7] = pair8(r8);
    }
  }
  A[i0 + t] = fadd32(fadd32(blk[0], blk[1]), fadd32(blk[2], blk[3]));
}

// W[n] = np.sum(cb[n]^2), exact pairwise order (round-2 body).
__global__ void vq_w(const float* __restrict__ cb, float* __restrict__ W) {
  const int n = blockIdx.x * 256 + threadIdx.x;
  const float* wp = cb + (size_t)n * D_DIM;
  float r8[8], blk[4];
#pragma unroll
  for (int bb = 0; bb < 4; ++bb) {
#pragma unroll
    for (int k = 0; k < 8; ++k) { float v = wp[bb * 128 + k]; r8[k] = fmul32(v, v); }
#pragma unroll
    for (int i = 8; i < 128; i += 8)
#pragma unroll
      for (int k = 0; k < 8; ++k) {
        float v = wp[bb * 128 + i + k];
        r8[k] = fadd32(r8[k], fmul32(v, v));
      }
    blk[bb] = pair8(r8);
  }
  W[n] = fadd32(fadd32(blk[0], blk[1]), fadd32(blk[2], blk[3]));
}

// ---------------------------------------------------------------------------
// Convert z -> frag-swizzled bf16 hi/lo arrays (into d_out scratch).
// Layout: [kc 16][mb 2048][q 4][m15 16][j 8] bf16; one thread emits one 16 B frag.
__global__ __launch_bounds__(256) void vq_convz(const float* __restrict__ z,
                                                char* __restrict__ zh_b,
                                                char* __restrict__ zl_b) {
  const int bid = blockIdx.x;
  const int pos0 = (bid >> 4) * 64;
  const int kc = bid & 15;
  const int p = threadIdx.x & 63, qq = threadIdx.x >> 6;
  const int pos = pos0 + p;
  const int b = pos >> 10, hw = pos & 1023;
  const float* src = z + (size_t)b * IMG_STRIDE + (size_t)(kc * 32 + qq * 8) * HW + hw;
  unsigned short hs[8], ls[8];
#pragma unroll
  for (int j = 0; j < 8; ++j) {
    float x = src[(size_t)j * HW];
    unsigned short h = f2bf(x);
    hs[j] = h;
    ls[j] = f2bf(x - bf2f(h));
  }
  const int mb = pos >> 4, m15 = pos & 15;
  size_t off = (size_t)kc * 2097152 + (size_t)mb * 1024 + qq * 256 + m15 * 16;
  *(uint4*)(zh_b + off) = *(uint4*)hs;
  *(uint4*)(zl_b + off) = *(uint4*)ls;
}

// Convert cb -> swizzled hi/lo. Layout: [kc 16][nb 64][q 4][n15 16][j 8] bf16.
__global__ __launch_bounds__(256) void vq_convw(const float* __restrict__ cb,
                                                char* __restrict__ wh_b,
                                                char* __restrict__ wl_b) {
  const int n = blockIdx.x * 4 + (threadIdx.x >> 6);
  const int oct = threadIdx.x & 63;
  const int kc = oct >> 2, q = oct & 3;
  const float* src = cb + (size_t)n * D_DIM + oct * 8;
  unsigned short hs[8], ls[8];
#pragma unroll
  for (int j = 0; j < 8; ++j) {
    float x = src[j];
    unsigned short h = f2bf(x);
    hs[j] = h;
    ls[j] = f2bf(x - bf2f(h));
  }
  size_t off = (size_t)kc * 65536 + (size_t)(n >> 4) * 1024 + q * 256 + (n & 15) * 16;
  *(uint4*)(wh_b + off) = *(uint4*)hs;
  *(uint4*)(wl_b + off) = *(uint4*)ls;
}

// ---------------------------------------------------------------------------
// MFMA scoring: M = zh·wh + zh·wl + zl·wh (bf16, fp32 acc); s = W - 2M.
// Block tile 128 pos x 256 n; wave tile 64x128 (4x8 of 16x16x32).
// Emits per-(row, bn) top-3 partials to ws.
__global__ __launch_bounds__(256, 2) void vq_score(
    const char* __restrict__ zh_b, const char* __restrict__ zl_b,
    const char* __restrict__ wh_b, const char* __restrict__ wl_b,
    const float* __restrict__ Wws, float* __restrict__ part)
{
  __shared__ __align__(16) char smem[49152];  // Ah 8K | Al 8K | Bh 16K | Bl 16K
  const int tid = threadIdx.x;
  const int lane = tid & 63, wave = tid >> 6;
  const int wr = wave >> 1, wc = wave & 1;
  const int bm = blockIdx.x & 255, bn = blockIdx.x >> 8;
  const int m0 = bm * 128, n0 = bn * 256;

  f4 acc[4][8];
#pragma unroll
  for (int r = 0; r < 4; ++r)
#pragma unroll
    for (int v = 0; v < 8; ++v) acc[r][v] = (f4)(0.0f);

  for (int kc = 0; kc < 16; ++kc) {
    const char* gA_h = zh_b + (size_t)kc * 2097152 + (size_t)bm * 8192;
    const char* gA_l = zl_b + (size_t)kc * 2097152 + (size_t)bm * 8192;
    const char* gB_h = wh_b + (size_t)kc * 65536 + (size_t)bn * 16384;
    const char* gB_l = wl_b + (size_t)kc * 65536 + (size_t)bn * 16384;
#pragma unroll
    for (int k = 0; k < 12; ++k) {          // 48 1KB segments, 12 per wave
      int seg = wave + 4 * k;
      const char* g; char* l;
      if (seg < 8)       { g = gA_h + seg * 1024;        l = smem + seg * 1024; }
      else if (seg < 16) { g = gA_l + (seg - 8) * 1024;  l = smem + 8192 + (seg - 8) * 1024; }
      else if (seg < 32) { g = gB_h + (seg - 16) * 1024; l = smem + 16384 + (seg - 16) * 1024; }
      else               { g = gB_l + (seg - 32) * 1024; l = smem + 32768 + (seg - 32) * 1024; }
      gl_lds16(g + lane * 16, l);
    }
    __syncthreads();
    b8 bh[8], bl[8];
#pragma unroll
    for (int v = 0; v < 8; ++v) {
      bh[v] = *(const b8*)(smem + 16384 + ((wc * 8 + v) << 10) + (lane << 4));
      bl[v] = *(const b8*)(smem + 32768 + ((wc * 8 + v) << 10) + (lane << 4));
    }
#pragma unroll
    for (int r = 0; r < 4; ++r) {
      b8 ah = *(const b8*)(smem + ((wr * 4 + r) << 10) + (lane << 4));
      b8 al = *(const b8*)(smem + 8192 + ((wr * 4 + r) << 10) + (lane << 4));
#pragma unroll
      for (int v = 0; v < 8; ++v)
        acc[r][v] = __builtin_amdgcn_mfma_f32_16x16x32_bf16(ah, bh[v], acc[r][v], 0, 0, 0);
#pragma unroll
      for (int v = 0; v < 8; ++v)
        acc[r][v] = __builtin_amdgcn_mfma_f32_16x16x32_bf16(ah, bl[v], acc[r][v], 0, 0, 0);
#pragma unroll
      for (int v = 0; v < 8; ++v)
        acc[r][v] = __builtin_amdgcn_mfma_f32_16x16x32_bf16(al, bh[v], acc[r][v], 0, 0, 0);
    }
    __syncthreads();
  }

  // epilogue: s = W - 2M; per-row top-3 across this block's 256 n
  const int l15 = lane & 15, quad = lane >> 4;
  float sW[8];
#pragma unroll
  for (int v = 0; v < 8; ++v) sW[v] = Wws[n0 + wc * 128 + v * 16 + l15];

  float* red = (float*)smem;  // [128 rows][2 wc][5]
#pragma unroll
  for (int r = 0; r < 4; ++r) {
#pragma unroll
    for (int reg = 0; reg < 4; ++reg) {
      T3 t; t.s1 = t.s2 = t.s3 = 3.4e38f; t.n1 = 0; t.n2 = 0;
#pragma unroll
      for (int v = 0; v < 8; ++v) {
        float s = fmaf(-2.f, acc[r][v][reg], sW[v]);
        int n = n0 + wc * 128 + v * 16 + l15;
        if (s < t.s1)      { t.s3 = t.s2; t.s2 = t.s1; t.n2 = t.n1; t.s1 = s; t.n1 = n; }
        else if (s < t.s2) { t.s3 = t.s2; t.s2 = s; t.n2 = n; }
        else if (s < t.s3) { t.s3 = s; }
      }
#pragma unroll
      for (int m = 1; m <= 8; m <<= 1) {   // butterfly within 16-lane quad
        T3 o;
        o.s1 = __shfl_xor(t.s1, m); o.s2 = __shfl_xor(t.s2, m); o.s3 = __shfl_xor(t.s3, m);
        o.n1 = __shfl_xor(t.n1, m); o.n2 = __shfl_xor(t.n2, m);
        t3_merge(t, o);
      }
      if (l15 == 0) {
        int row = wr * 64 + r * 16 + quad * 4 + reg;
        float* d = red + (row * 2 + wc) * 5;
        d[0] = t.s1; d[1] = t.s2; d[2] = t.s3; d[3] = (float)t.n1; d[4] = (float)t.n2;
      }
    }
  }
  __syncthreads();
  if (tid < 128) {
    const float* d0 = red + (tid * 2) * 5;
    const float* d1 = red + (tid * 2 + 1) * 5;
    T3 a; a.s1 = d0[0]; a.s2 = d0[1]; a.s3 = d0[2]; a.n1 = (int)d0[3]; a.n2 = (int)d0[4];
    T3 b; b.s1 = d1[0]; b.s2 = d1[1]; b.s3 = d1[2]; b.n1 = (int)d1[3]; b.n2 = (int)d1[4];
    t3_merge(a, b);
    float* p = part + ((size_t)(m0 + tid) * 4 + bn) * 5;
    p[0] = a.s1; p[1] = a.s2; p[2] = a.s3; p[3] = (float)a.n1; p[4] = (float)a.n2;
  }
}

// Combine 4 n-slices per row; write idx + packed candidates/flags.
__global__ void vq_comb(const float* __restrict__ part, float* __restrict__ out_idx,
                        unsigned int* __restrict__ pk) {
  int row = blockIdx.x * 256 + threadIdx.x;
  const float* p = part + (size_t)row * 20;
  T3 a; a.s1 = p[0]; a.s2 = p[1]; a.s3 = p[2]; a.n1 = (int)p[3]; a.n2 = (int)p[4];
#pragma unroll
  for (int j = 1; j < 4; ++j) {
    const float* q = p + j * 5;
    T3 b; b.s1 = q[0]; b.s2 = q[1]; b.s3 = q[2]; b.n1 = (int)q[3]; b.n2 = (int)q[4];
    t3_merge(a, b);
  }
  out_idx[row] = (float)a.n1;
  unsigned int f = 0;
  if (a.s2 - a.s1 < WINDOW) f = (a.s3 - a.s1 < WINDOW) ? 2u : 1u;
  pk[row] = (unsigned int)a.n1 | ((unsigned int)a.n2 << 10) | (f << 20);
}

// fp64 top-2 recheck with reference-exact final combine (flag==1 rows).
__global__ __launch_bounds__(256) void vq_recheckA(
    const float* __restrict__ z, const float* __restrict__ cb,
    const float* __restrict__ Aws, const float* __restrict__ Wws,
    const unsigned int* __restrict__ pk, float* __restrict__ out_idx)
{
  const int wave = threadIdx.x >> 6, lane = threadIdx.x & 63;
  const int base = blockIdx.x * 256 + wave * 64;
  for (int rr = 0; rr < 64; ++rr) {
    int row = base + rr;
    unsigned int p = pk[row];
    if (((p >> 20) & 3u) != 1u) continue;
    int n1 = p & 1023, n2 = (p >> 10) & 1023;
    int b = row >> 10, hw = row & 1023;
    const float* zr = z + (size_t)b * IMG_STRIDE + hw;
    const float* c1 = cb + (size_t)n1 * D_DIM;
    const float* c2 = cb + (size_t)n2 * D_DIM;
    double d1 = 0.0, d2 = 0.0;
#pragma unroll
    for (int j = 0; j < 8; ++j) {
      int c = lane + 64 * j;
      double zv = (double)zr[(size_t)c * HW];
      d1 += zv * (double)c1[c];
      d2 += zv * (double)c2[c];
    }
#pragma unroll
    for (int off = 32; off > 0; off >>= 1) {
      d1 += __shfl_down(d1, off);
      d2 += __shfl_down(d2, off);
    }
    if (lane == 0) {
      float A_ = Aws[row];
      float e1 = fadd32(fadd32(A_, -2.f * (float)d1), Wws[n1]);
      float e2 = fadd32(fadd32(A_, -2.f * (float)d2), Wws[n2]);
      int win = n1;
      if (e2 < e1 || (e2 == e1 && n2 < n1)) win = n2;
      out_idx[row] = (float)win;
    }
  }
}

// Full 1024-code fp64 rescan for flag==2 rows (expected ~5 rows).
__global__ __launch_bounds__(256) void vq_recheckB(
    const float* __restrict__ z, const float* __restrict__ cb,
    const float* __restrict__ Aws, const float* __restrict__ Wws,
    const unsigned int* __restrict__ pk, float* __restrict__ out_idx)
{
  __shared__ double zd[512];
  __shared__ float rd[256];
  __shared__ int rn[256];
  const int i0 = blockIdx.x * 64;
  for (int rr = 0; rr < 64; ++rr) {
    int row = i0 + rr;
    if (((pk[row] >> 20) & 3u) != 2u) continue;   // block-uniform
    int b = row >> 10, hw = row & 1023;
    const float* zr = z + (size_t)b * IMG_STRIDE + hw;
    for (int c = threadIdx.x; c < 512; c += 256) zd[c] = (double)zr[(size_t)c * HW];
    __syncthreads();
    float best = 3.4e38f; int bn_ = 0;
    float A_ = Aws[row];
    for (int k = 0; k < 4; ++k) {
      int n = k * 256 + threadIdx.x;
      const float* cn = cb + (size_t)n * D_DIM;
      double dot = 0.0;
#pragma unroll 8
      for (int c = 0; c < 512; ++c) dot += zd[c] * (double)cn[c];
      float e = fadd32(fadd32(A_, -2.f * (float)dot), Wws[n]);
      if (e < best || (e == best && n < bn_)) { best = e; bn_ = n; }
    }
    rd[threadIdx.x] = best; rn[threadIdx.x] = bn_;
    __syncthreads();
    for (int s = 128; s > 0; s >>= 1) {
      if (threadIdx.x < s) {
        float eo = rd[threadIdx.x + s]; int no = rn[threadIdx.x + s];
        if (eo < rd[threadIdx.x] || (eo == rd[threadIdx.x] && no < rn[threadIdx.x])) {
          rd[threadIdx.x] = eo; rn[threadIdx.x] = no;
        }
      }
      __syncthreads();
    }
    if (threadIdx.x == 0) out_idx[row] = (float)rn[0];
    __syncthreads();
  }
}

// Final gather: out_q rows = codebook rows (contiguous; no inverse permute).
__global__ __launch_bounds__(256) void vq_gather(const float* __restrict__ cb,
                                                 const float* __restrict__ out_idx,
                                                 float* __restrict__ out_q) {
  __shared__ int bidx[64];
  const int i0 = blockIdx.x * 64;
  if (threadIdx.x < 64) bidx[threadIdx.x] = (int)out_idx[i0 + threadIdx.x];
  __syncthreads();
  float* outp = out_q + (size_t)i0 * D_DIM;
  for (int j = 0; j < 32; ++j) {
    int f4i = j * 256 + threadIdx.x;
    int row = f4i >> 7, d4 = f4i & 127;
    float4 vv = *(const float4*)(cb + (size_t)bidx[row] * D_DIM + 4 * d4);
    *(float4*)(outp + 4 * f4i) = vv;
  }
}

extern "C" void kernel_launch(void* const* d_in, const int* in_sizes, int n_in,
                              void* d_out, int out_size, void* d_ws, size_t ws_size,
                              hipStream_t stream) {
  const float* z  = (const float*)d_in[0];
  const float* cb = (const float*)d_in[1];
  float* out_q   = (float*)d_out;
  float* out_idx = (float*)d_out + (size_t)M_ROWS * D_DIM;
  char* zh_b = (char*)d_out;                // out_q region doubles as hi/lo scratch
  char* zl_b = zh_b + 33554432;
  char* ws = (char*)d_ws;
  char* wh_b = ws + WH_OFF;
  char* wl_b = ws + WL_OFF;
  float* Aws = (float*)(ws + A_OFF);
  float* Wws = (float*)(ws + W_OFF);
  unsigned int* pk = (unsigned int*)(ws + PK_OFF);
  float* part = (float*)(ws + PART_OFF);

  vq_convz   <<<8192, 256, 0, stream>>>(z, zh_b, zl_b);
  vq_convw   <<<256, 256, 0, stream>>>(cb, wh_b, wl_b);
  vq_a       <<<128, 256, 0, stream>>>(z, Aws);
  vq_w       <<<4, 256, 0, stream>>>(cb, Wws);
  vq_score   <<<1024, 256, 0, stream>>>(zh_b, zl_b, wh_b, wl_b, Wws, part);
  vq_comb    <<<128, 256, 0, stream>>>(part, out_idx, pk);
  vq_recheckA<<<128, 256, 0, stream>>>(z, cb, Aws, Wws, pk, out_idx);
  vq_recheckB<<<512, 256, 0, stream>>>(z, cb, Aws, Wws, pk, out_idx);
  vq_gather  <<<512, 256, 0, stream>>>(cb, out_idx, out_q);
}

// Round 4
// 418.975 us; speedup vs baseline: 1.3881x; 1.0413x over previous
//
#include <hip/hip_runtime.h>
#include <hip/hip_bf16.h>

// Problem constants
#define M_ROWS  32768   // B*H*W
#define D_DIM   512     // C == latent dim
#define K_CODES 1024
#define HW      1024
#define IMG_STRIDE (D_DIM * HW)   // 524288

// d_out scratch: zh swizzled bf16 (32 MB) lives in the out_q region until the
// final gather overwrites it. idx region (last 128 KB of d_out) is real output.
// ws layout (bytes):
#define WH_OFF   0u          // 1 MB   swizzled cb-hi bf16
#define A_OFF    1048576u    // 128 KB A[i] (numpy-pairwise)
#define W_OFF    1179648u    // 4 KB   W[n]
#define PK_OFF   1183744u    // 128 KB packed candidates/flags
#define PART_OFF 1312768u    // 2.62 MB per-(row,bn) top3 partials
#define WL1_OFF  3934208u    // 128 KB worklist flag==1
#define WL2_OFF  4065280u    // 128 KB worklist flag==2
#define CNT_OFF  4196352u    // 8 B    counters

// 1-term bf16 error: pairwise sigma ~4.3e-5 -> 7.5 sigma = 3.2e-4, plus fp32
// reorder/grid window 1.22e-4 -> 4.4e-4; pad to 5e-4.
#define WINDOW 5.0e-4f

// ---- exact RNE fp32 ops the compiler can't contract/reassociate ----
__device__ __forceinline__ float fmul32(float a, float b) {
  float r; asm volatile("v_mul_f32 %0, %1, %2" : "=v"(r) : "v"(a), "v"(b)); return r;
}
__device__ __forceinline__ float fadd32(float a, float b) {
  float r; asm volatile("v_add_f32 %0, %1, %2" : "=v"(r) : "v"(a), "v"(b)); return r;
}
__device__ __forceinline__ float pair8(const float* r) {
  return fadd32(fadd32(fadd32(r[0], r[1]), fadd32(r[2], r[3])),
                fadd32(fadd32(r[4], r[5]), fadd32(r[6], r[7])));
}

__device__ __forceinline__ unsigned short f2bf(float x) {
  __hip_bfloat16 h = __float2bfloat16(x);
  unsigned short u; __builtin_memcpy(&u, &h, 2); return u;
}

typedef __attribute__((ext_vector_type(8))) short b8;
typedef __attribute__((ext_vector_type(4))) float f4;

__device__ __forceinline__ void gl_lds16(const void* g, void* l) {
  __builtin_amdgcn_global_load_lds(
      (const __attribute__((address_space(1))) unsigned int*)g,
      (__attribute__((address_space(3))) unsigned int*)l, 16, 0, 0);
}

// top-3 tracking (values s1<=s2<=s3; indices for first two; first-index ties)
struct T3 { float s1, s2, s3; int n1, n2; };
__device__ __forceinline__ void t3_merge(T3& a, const T3& bb) {
  T3 x = a, y = bb;
  bool bf = (y.s1 < x.s1) || (y.s1 == x.s1 && y.n1 < x.n1);
  if (bf) { T3 t = x; x = y; y = t; }
  float rs2; int rn2; float rs3;
  bool c2 = (y.s1 < x.s2) || (y.s1 == x.s2 && y.n1 < x.n2);
  if (c2) { rs2 = y.s1; rn2 = y.n1; rs3 = fminf(x.s2, y.s2); }
  else    { rs2 = x.s2; rn2 = x.n2; rs3 = fminf(x.s3, y.s1); }
  a.s1 = x.s1; a.n1 = x.n1; a.s2 = rs2; a.n2 = rn2; a.s3 = rs3;
}

// ---------------------------------------------------------------------------
// Fused: A[i] = np.sum(z^2) (exact numpy fp32 pairwise order, round-3 code
// path untouched) + zh swizzled-bf16 emission. One pass over z.
// zh layout: [kc 16][mb 2048][q 4][m15 16][j 8] bf16.
__global__ __launch_bounds__(256) void vq_prep(const float* __restrict__ z,
                                               float* __restrict__ A,
                                               char* __restrict__ zh_b) {
  __shared__ float zs[4][64 * 68];
  const int wave = threadIdx.x >> 6, t = threadIdx.x & 63;
  const int i0 = blockIdx.x * 256 + wave * 64;
  const int b = i0 >> 10, hw0 = i0 & 1023;
  const float* zbase = z + (size_t)b * IMG_STRIDE + hw0;
  float* zsw = zs[wave];
  const int pos = i0 + t;
  const size_t mbase = (size_t)(pos >> 4) * 1024 + (size_t)(pos & 15) * 16;
  float r8[8], blk[4];
  alignas(16) unsigned short hs[8];
#pragma unroll
  for (int ch = 0; ch < 8; ++ch) {
    __syncthreads();
    {
      const int l = t & 15, j0 = t >> 4;
#pragma unroll
      for (int jj = 0; jj < 16; ++jj) {
        int j = j0 * 16 + jj;
        float4 vv = *(const float4*)(zbase + (size_t)(ch * 64 + j) * HW + 4 * l);
        *(float4*)(zsw + j * 68 + 4 * l) = vv;
      }
    }
    __syncthreads();
#pragma unroll
    for (int j = 0; j < 64; ++j) {
      const int c = ch * 64 + j;
      float v = zsw[j * 68 + t];
      hs[j & 7] = f2bf(v);
      if ((j & 7) == 7) {
        const int kc = c >> 5, q = (c >> 3) & 3;
        *(uint4*)(zh_b + (size_t)kc * 2097152 + q * 256 + mbase) = *(uint4*)hs;
      }
      float pq = fmul32(v, v);
      const int k = c & 7, m = c & 127;
      if (m < 8) r8[k] = pq;
      else       r8[k] = fadd32(r8[k], pq);
      if (m == 127) blk[c >> 7] = pair8(r8);
    }
  }
  A[pos] = fadd32(fadd32(blk[0], blk[1]), fadd32(blk[2], blk[3]));
}

// Fused: W[n] = np.sum(cb^2) (exact pairwise order) + wh swizzled emission.
// wh layout: [kc 16][nb 64][q 4][n15 16][j 8] bf16. Also zeroes counters.
__global__ void vq_prepw(const float* __restrict__ cb, float* __restrict__ W,
                         char* __restrict__ wh_b, int* __restrict__ cnt) {
  if (blockIdx.x == 0 && threadIdx.x < 2) cnt[threadIdx.x] = 0;
  const int n = blockIdx.x * 256 + threadIdx.x;
  const float* wp = cb + (size_t)n * D_DIM;
  const size_t nbase = (size_t)(n >> 4) * 1024 + (size_t)(n & 15) * 16;
  float r8[8], blk[4];
  alignas(16) unsigned short hs[8];
#pragma unroll
  for (int bb = 0; bb < 4; ++bb) {
#pragma unroll
    for (int g = 0; g < 16; ++g) {
      float vv[8];
#pragma unroll
      for (int k = 0; k < 8; ++k) vv[k] = wp[bb * 128 + g * 8 + k];
#pragma unroll
      for (int k = 0; k < 8; ++k) {
        float pq = fmul32(vv[k], vv[k]);
        if (g == 0) r8[k] = pq;
        else        r8[k] = fadd32(r8[k], pq);
        hs[k] = f2bf(vv[k]);
      }
      const int kc = bb * 4 + (g >> 2), q = g & 3;
      *(uint4*)(wh_b + (size_t)kc * 65536 + q * 256 + nbase) = *(uint4*)hs;
    }
    blk[bb] = pair8(r8);
  }
  W[n] = fadd32(fadd32(blk[0], blk[1]), fadd32(blk[2], blk[3]));
}

// ---------------------------------------------------------------------------
// 1-term MFMA scoring: M ~= zh·wh (bf16, fp32 acc); s = W - 2M.
// Block tile 128 pos x 256 n; wave tile 64x128 (4x8 of 16x16x32).
__global__ __launch_bounds__(256, 2) void vq_score(
    const char* __restrict__ zh_b, const char* __restrict__ wh_b,
    const float* __restrict__ Wws, float* __restrict__ part)
{
  __shared__ __align__(16) char smem[24576];  // A 8K | B 16K
  const int tid = threadIdx.x;
  const int lane = tid & 63, wave = tid >> 6;
  const int wr = wave >> 1, wc = wave & 1;
  const int bm = blockIdx.x & 255, bn = blockIdx.x >> 8;
  const int m0 = bm * 128, n0 = bn * 256;

  f4 acc[4][8];
#pragma unroll
  for (int r = 0; r < 4; ++r)
#pragma unroll
    for (int v = 0; v < 8; ++v) acc[r][v] = (f4)(0.0f);

  for (int kc = 0; kc < 16; ++kc) {
    const char* gA = zh_b + (size_t)kc * 2097152 + (size_t)bm * 8192;
    const char* gB = wh_b + (size_t)kc * 65536 + (size_t)bn * 16384;
#pragma unroll
    for (int k = 0; k < 6; ++k) {           // 24 1KB segments, 6 per wave
      int seg = wave + 4 * k;
      const char* g; char* l;
      if (seg < 8) { g = gA + seg * 1024;        l = smem + seg * 1024; }
      else         { g = gB + (seg - 8) * 1024;  l = smem + 8192 + (seg - 8) * 1024; }
      gl_lds16(g + lane * 16, l);
    }
    __syncthreads();
    b8 bh[8];
#pragma unroll
    for (int v = 0; v < 8; ++v)
      bh[v] = *(const b8*)(smem + 8192 + ((wc * 8 + v) << 10) + (lane << 4));
#pragma unroll
    for (int r = 0; r < 4; ++r) {
      b8 ah = *(const b8*)(smem + ((wr * 4 + r) << 10) + (lane << 4));
#pragma unroll
      for (int v = 0; v < 8; ++v)
        acc[r][v] = __builtin_amdgcn_mfma_f32_16x16x32_bf16(ah, bh[v], acc[r][v], 0, 0, 0);
    }
    __syncthreads();
  }

  // epilogue: s = W - 2M; per-row top-3 across this block's 256 n
  const int l15 = lane & 15, quad = lane >> 4;
  float sW[8];
#pragma unroll
  for (int v = 0; v < 8; ++v) sW[v] = Wws[n0 + wc * 128 + v * 16 + l15];

  float* red = (float*)smem;  // [128 rows][2 wc][5]
#pragma unroll
  for (int r = 0; r < 4; ++r) {
#pragma unroll
    for (int reg = 0; reg < 4; ++reg) {
      T3 t; t.s1 = t.s2 = t.s3 = 3.4e38f; t.n1 = 0; t.n2 = 0;
#pragma unroll
      for (int v = 0; v < 8; ++v) {
        float s = fmaf(-2.f, acc[r][v][reg], sW[v]);
        int n = n0 + wc * 128 + v * 16 + l15;
        if (s < t.s1)      { t.s3 = t.s2; t.s2 = t.s1; t.n2 = t.n1; t.s1 = s; t.n1 = n; }
        else if (s < t.s2) { t.s3 = t.s2; t.s2 = s; t.n2 = n; }
        else if (s < t.s3) { t.s3 = s; }
      }
#pragma unroll
      for (int m = 1; m <= 8; m <<= 1) {   // butterfly within 16-lane quad
        T3 o;
        o.s1 = __shfl_xor(t.s1, m); o.s2 = __shfl_xor(t.s2, m); o.s3 = __shfl_xor(t.s3, m);
        o.n1 = __shfl_xor(t.n1, m); o.n2 = __shfl_xor(t.n2, m);
        t3_merge(t, o);
      }
      if (l15 == 0) {
        int row = wr * 64 + r * 16 + quad * 4 + reg;
        float* d = red + (row * 2 + wc) * 5;
        d[0] = t.s1; d[1] = t.s2; d[2] = t.s3; d[3] = (float)t.n1; d[4] = (float)t.n2;
      }
    }
  }
  __syncthreads();
  if (tid < 128) {
    const float* d0 = red + (tid * 2) * 5;
    const float* d1 = red + (tid * 2 + 1) * 5;
    T3 a; a.s1 = d0[0]; a.s2 = d0[1]; a.s3 = d0[2]; a.n1 = (int)d0[3]; a.n2 = (int)d0[4];
    T3 b; b.s1 = d1[0]; b.s2 = d1[1]; b.s3 = d1[2]; b.n1 = (int)d1[3]; b.n2 = (int)d1[4];
    t3_merge(a, b);
    float* p = part + ((size_t)(m0 + tid) * 4 + bn) * 5;
    p[0] = a.s1; p[1] = a.s2; p[2] = a.s3; p[3] = (float)a.n1; p[4] = (float)a.n2;
  }
}

// Combine 4 n-slices per row; write idx, packed candidates, and worklists.
__global__ void vq_comb(const float* __restrict__ part, float* __restrict__ out_idx,
                        unsigned int* __restrict__ pk, int* __restrict__ wl1,
                        int* __restrict__ wl2, int* __restrict__ cnt) {
  int row = blockIdx.x * 256 + threadIdx.x;
  const float* p = part + (size_t)row * 20;
  T3 a; a.s1 = p[0]; a.s2 = p[1]; a.s3 = p[2]; a.n1 = (int)p[3]; a.n2 = (int)p[4];
#pragma unroll
  for (int j = 1; j < 4; ++j) {
    const float* q = p + j * 5;
    T3 b; b.s1 = q[0]; b.s2 = q[1]; b.s3 = q[2]; b.n1 = (int)q[3]; b.n2 = (int)q[4];
    t3_merge(a, b);
  }
  out_idx[row] = (float)a.n1;
  unsigned int f = 0;
  if (a.s2 - a.s1 < WINDOW) f = (a.s3 - a.s1 < WINDOW) ? 2u : 1u;
  pk[row] = (unsigned int)a.n1 | ((unsigned int)a.n2 << 10) | (f << 20);
  if (f == 1u) wl1[atomicAdd(&cnt[0], 1)] = row;
  if (f == 2u) wl2[atomicAdd(&cnt[1], 1)] = row;
}

// fp64 top-2 recheck with reference-exact final combine; one wave per row.
__global__ __launch_bounds__(256) void vq_recheckA(
    const float* __restrict__ z, const float* __restrict__ cb,
    const float* __restrict__ Aws, const float* __restrict__ Wws,
    const unsigned int* __restrict__ pk, const int* __restrict__ wl1,
    const int* __restrict__ cnt, float* __restrict__ out_idx)
{
  const int wave = threadIdx.x >> 6, lane = threadIdx.x & 63;
  const int gw = blockIdx.x * 4 + wave;
  const int c1 = cnt[0];
  for (int i = gw; i < c1; i += 2048) {
    int row = wl1[i];
    unsigned int p = pk[row];
    int n1 = p & 1023, n2 = (p >> 10) & 1023;
    int b = row >> 10, hw = row & 1023;
    const float* zr = z + (size_t)b * IMG_STRIDE + hw;
    const float* c1p = cb + (size_t)n1 * D_DIM;
    const float* c2p = cb + (size_t)n2 * D_DIM;
    double d1 = 0.0, d2 = 0.0;
#pragma unroll
    for (int j = 0; j < 8; ++j) {
      int c = lane + 64 * j;
      double zv = (double)zr[(size_t)c * HW];
      d1 += zv * (double)c1p[c];
      d2 += zv * (double)c2p[c];
    }
#pragma unroll
    for (int off = 32; off > 0; off >>= 1) {
      d1 += __shfl_down(d1, off);
      d2 += __shfl_down(d2, off);
    }
    if (lane == 0) {
      float A_ = Aws[row];
      float e1 = fadd32(fadd32(A_, -2.f * (float)d1), Wws[n1]);
      float e2 = fadd32(fadd32(A_, -2.f * (float)d2), Wws[n2]);
      int win = (e2 < e1 || (e2 == e1 && n2 < n1)) ? n2 : n1;
      out_idx[row] = (float)win;
    }
  }
}

// Full 1024-code fp64 rescan; one block per flag==2 row (rare).
__global__ __launch_bounds__(256) void vq_recheckB(
    const float* __restrict__ z, const float* __restrict__ cb,
    const float* __restrict__ Aws, const float* __restrict__ Wws,
    const int* __restrict__ wl2, const int* __restrict__ cnt,
    float* __restrict__ out_idx)
{
  __shared__ double zd[512];
  __shared__ float rd[256];
  __shared__ int rn[256];
  const int c2 = cnt[1];
  for (int t = blockIdx.x; t < c2; t += 64) {
    int row = wl2[t];
    int b = row >> 10, hw = row & 1023;
    const float* zr = z + (size_t)b * IMG_STRIDE + hw;
    for (int c = threadIdx.x; c < 512; c += 256) zd[c] = (double)zr[(size_t)c * HW];
    __syncthreads();
    float best = 3.4e38f; int bn_ = 0;
    float A_ = Aws[row];
    for (int k = 0; k < 4; ++k) {
      int n = k * 256 + threadIdx.x;
      const float* cn = cb + (size_t)n * D_DIM;
      double dot = 0.0;
#pragma unroll 8
      for (int c = 0; c < 512; ++c) dot += zd[c] * (double)cn[c];
      float e = fadd32(fadd32(A_, -2.f * (float)dot), Wws[n]);
      if (e < best || (e == best && n < bn_)) { best = e; bn_ = n; }
    }
    rd[threadIdx.x] = best; rn[threadIdx.x] = bn_;
    __syncthreads();
    for (int s = 128; s > 0; s >>= 1) {
      if (threadIdx.x < s) {
        float eo = rd[threadIdx.x + s]; int no = rn[threadIdx.x + s];
        if (eo < rd[threadIdx.x] || (eo == rd[threadIdx.x] && no < rn[threadIdx.x])) {
          rd[threadIdx.x] = eo; rn[threadIdx.x] = no;
        }
      }
      __syncthreads();
    }
    if (threadIdx.x == 0) out_idx[row] = (float)rn[0];
    __syncthreads();
  }
}

// Final gather: out_q rows = codebook rows (contiguous; no inverse permute).
// Runs last — overwrites the zh scratch living in the out_q region.
__global__ __launch_bounds__(256) void vq_gather(const float* __restrict__ cb,
                                                 const float* __restrict__ out_idx,
                                                 float* __restrict__ out_q) {
  __shared__ int bidx[64];
  const int i0 = blockIdx.x * 64;
  if (threadIdx.x < 64) bidx[threadIdx.x] = (int)out_idx[i0 + threadIdx.x];
  __syncthreads();
  float* outp = out_q + (size_t)i0 * D_DIM;
  for (int j = 0; j < 32; ++j) {
    int f4i = j * 256 + threadIdx.x;
    int row = f4i >> 7, d4 = f4i & 127;
    float4 vv = *(const float4*)(cb + (size_t)bidx[row] * D_DIM + 4 * d4);
    *(float4*)(outp + 4 * f4i) = vv;
  }
}

extern "C" void kernel_launch(void* const* d_in, const int* in_sizes, int n_in,
                              void* d_out, int out_size, void* d_ws, size_t ws_size,
                              hipStream_t stream) {
  const float* z  = (const float*)d_in[0];
  const float* cb = (const float*)d_in[1];
  float* out_q   = (float*)d_out;
  float* out_idx = (float*)d_out + (size_t)M_ROWS * D_DIM;
  char* zh_b = (char*)d_out;                // out_q region doubles as zh scratch
  char* ws = (char*)d_ws;
  char* wh_b = ws + WH_OFF;
  float* Aws = (float*)(ws + A_OFF);
  float* Wws = (float*)(ws + W_OFF);
  unsigned int* pk = (unsigned int*)(ws + PK_OFF);
  float* part = (float*)(ws + PART_OFF);
  int* wl1 = (int*)(ws + WL1_OFF);
  int* wl2 = (int*)(ws + WL2_OFF);
  int* cnt = (int*)(ws + CNT_OFF);

  vq_prep    <<<128, 256, 0, stream>>>(z, Aws, zh_b);
  vq_prepw   <<<4, 256, 0, stream>>>(cb, Wws, wh_b, cnt);
  vq_score   <<<1024, 256, 0, stream>>>(zh_b, wh_b, Wws, part);
  vq_comb    <<<128, 256, 0, stream>>>(part, out_idx, pk, wl1, wl2, cnt);
  vq_recheckA<<<512, 256, 0, stream>>>(z, cb, Aws, Wws, pk, wl1, cnt, out_idx);
  vq_recheckB<<<64, 256, 0, stream>>>(z, cb, Aws, Wws, wl2, cnt, out_idx);
  vq_gather  <<<512, 256, 0, stream>>>(cb, out_idx, out_q);
}